// Round 3
// baseline (429.820 us; speedup 1.0000x reference)
//
#include <hip/hip_runtime.h>

typedef __bf16 bf16x8 __attribute__((ext_vector_type(8)));
typedef float f32x16 __attribute__((ext_vector_type(16)));
typedef unsigned int u32x4 __attribute__((ext_vector_type(4)));

#define NGROUP 8
#define DMODEL 256
#define DFF    1024
#define TTOT   131072
#define TGRP   (TTOT / NGROUP)   // 16384
#define MTILE  256               // tokens per block (8 waves x 32)
#define NCHUNK 32                // f-chunks of 32 (DFF/32)
// LDS map (96 KB static): THREE 32KB chunk buffers (gate+up only, triple-buffered).
//   buf b at u32x4 offset b*2048:
//     [   0, 16K)  gate A-frags [ks(16)][lane(64)] x 16B
//     [ 16K, 32K)  up   A-frags
// Down-weights (Wd) never touch LDS: loaded per-wave straight from L2 into
// VGPRs as MFMA B-frags (vmem pipe), in 4-frag batches with counted vmcnt.
// h never touches LDS either (k-permuted Wd makes packed GEMM1 acc == GEMM2 A-frag).
// ONE s_barrier per chunk; each chunk ends vmcnt(0), so a wave's staged data is
// published two barriers before any wave reads it (race-free drift of +/-1 chunk).

__device__ __forceinline__ unsigned int f2bf(float f) {
    unsigned int x = __builtin_bit_cast(unsigned int, f);
    return (x + 0x7fffu + ((x >> 16) & 1u)) >> 16;   // RNE
}
__device__ __forceinline__ unsigned int pack2(float lo, float hi) {
    return f2bf(lo) | (f2bf(hi) << 16);
}
__device__ __forceinline__ unsigned int cvtpk(float lo, float hi) {
    unsigned int r;
    asm("v_cvt_pk_bf16_f32 %0, %1, %2" : "=v"(r) : "v"(lo), "v"(hi));  // RNE
    return r;
}

__device__ __forceinline__ void g2l(const void* g, void* l) {
    __builtin_amdgcn_global_load_lds(
        (const __attribute__((address_space(1))) unsigned int*)g,
        (__attribute__((address_space(3))) unsigned int*)l, 16, 0, 0);
}

__device__ __forceinline__ u32x4 gld16(const u32x4* p) {
    u32x4 d;
    asm volatile("global_load_dwordx4 %0, %1, off" : "=v"(d) : "v"(p) : "memory");
    return d;
}

// ---------------- prep: all weights -> per-(group,chunk) 48KB frag blocks ----------------
// (unchanged layout; frags 0..31 are staged to LDS, frags 32..47 loaded direct)
//   fid 0..15  : gate A-frag, ks=fid      W[d=ks*16+q*8+j][f=c*32+l31]
//   fid 16..31 : up   A-frag, ks=fid-16
//   fid 32..47 : down B-frag, ks2=(fid-32)>>3, nb=(fid-32)&7
//     k-axis PERMUTED to match packed-accumulator A-frags:
//     B[k=q*8+j] = Wd[F = c*32 + ks2*16 + q*4 + (j&3) + 8*(j>>2)][col=nb*32+l31]
__global__ void k_prep_w(const float* __restrict__ wg, const float* __restrict__ wu,
                         const float* __restrict__ wd, u32x4* __restrict__ out) {
    int t = blockIdx.x * 256 + threadIdx.x;   // 786432 total
    int lane = t & 63;
    int q = lane >> 5, l31 = lane & 31;
    int fg = t >> 6;
    int fid = fg % 48;
    int gc  = fg / 48;
    int c = gc & 31, g = gc >> 5;
    u32x4 v;
    if (fid < 32) {
        const float* w = (fid < 16) ? wg : wu;
        int ks = fid & 15;
        const float* src = w + (size_t)(g * 256 + ks * 16 + q * 8) * 1024 + c * 32 + l31;
        v = u32x4{ pack2(src[0],        src[1024]),
                   pack2(src[2 * 1024], src[3 * 1024]),
                   pack2(src[4 * 1024], src[5 * 1024]),
                   pack2(src[6 * 1024], src[7 * 1024]) };
    } else {
        int idx = fid - 32;
        int ks2 = idx >> 3, nb = idx & 7;
        // rows f = base + {0,1,2,3, 8,9,10,11}  (permuted k-axis)
        const float* src = wd + (size_t)(g * 1024 + c * 32 + ks2 * 16 + q * 4) * 256 + nb * 32 + l31;
        v = u32x4{ pack2(src[0 * 256],  src[1 * 256]),
                   pack2(src[2 * 256],  src[3 * 256]),
                   pack2(src[8 * 256],  src[9 * 256]),
                   pack2(src[10 * 256], src[11 * 256]) };
    }
    out[t] = v;
}

// ---------------- main fused grouped-GLU ----------------
__global__ __launch_bounds__(512, 2)
void k_glu(const float* __restrict__ x,      // fp32 x row-major [T][256]
           const u32x4* __restrict__ wcomb,  // [g][c][48 frag-groups][64 lanes]
           float* __restrict__ y) {
    __shared__ u32x4 smem[6144];   // 96 KB: three 32KB buffers

    const int tid  = threadIdx.x;
    const int lane = tid & 63;
    const int w    = tid >> 6;      // wave 0..7 = token-32 block
    const int q    = lane >> 5;
    const int l31  = lane & 31;

    // XCD swizzle: group = blockIdx & 7 so each XCD's L2 holds one group's weights
    const int g    = blockIdx.x & 7;
    const int m0   = g * TGRP + (blockIdx.x >> 3) * MTILE;
    const int tok  = m0 + w * 32 + l31;

    const u32x4* wcg = wcomb + (size_t)(g * 32) * 3072;

    // ---- prologue: stage chunk 0 -> buf0, chunk 1 -> buf1 (gate+up only, 32KB each)
    #pragma unroll
    for (int i = 0; i < 4; ++i) {
        int off = i * 512 + w * 64;   // u32x4 index, wave-uniform LDS dest
        g2l(wcg + off + lane, smem + off);
    }
    #pragma unroll
    for (int i = 0; i < 4; ++i) {
        int off = i * 512 + w * 64;
        g2l(wcg + 3072 + off + lane, smem + 2048 + off);
    }
    // x -> bf16 B-frags, register-resident for the whole block
    u32x4 xf[16];
    {
        const float* xrow = x + (size_t)tok * DMODEL + q * 8;
        #pragma unroll
        for (int ks = 0; ks < 16; ++ks) {
            float4 a = *(const float4*)(xrow + ks * 16);
            float4 b = *(const float4*)(xrow + ks * 16 + 4);
            xf[ks] = u32x4{ cvtpk(a.x, a.y), cvtpk(a.z, a.w),
                            cvtpk(b.x, b.y), cvtpk(b.z, b.w) };
        }
    }

    f32x16 acc[8];
    #pragma unroll
    for (int nb = 0; nb < 8; ++nb)
        #pragma unroll
        for (int i = 0; i < 16; ++i) acc[nb][i] = 0.0f;

    asm volatile("s_waitcnt vmcnt(0)" ::: "memory");   // chunk 0/1 staged

    int bcur = 0;   // buf slot of current chunk (c % 3), maintained incrementally
    for (int c = 0; c < NCHUNK; ++c) {
        __builtin_amdgcn_s_barrier();   // all waves done chunk c-1 (each ended vmcnt(0))
        asm volatile("" ::: "memory");

        // ---- stage chunk c+2 into buf (c+2)%3 == (c-1)%3 (freed at the barrier above)
        if (c < NCHUNK - 2) {
            const int bst = (bcur == 0) ? 2 : bcur - 1;
            u32x4* db = smem + bst * 2048;
            const u32x4* gsrc = wcg + (size_t)(c + 2) * 3072;
            #pragma unroll
            for (int i = 0; i < 4; ++i) {
                int off = i * 512 + w * 64;
                g2l(gsrc + off + lane, db + off);
            }
        }

        const u32x4* sb = smem + bcur * 2048;

        // ---- GEMM1: z^T (32f x 32tok) over K=256, gate/up from LDS, x from regs
        f32x16 zg, zu;
        #pragma unroll
        for (int i = 0; i < 16; ++i) { zg[i] = 0.0f; zu[i] = 0.0f; }
        __builtin_amdgcn_s_setprio(1);
        #pragma unroll
        for (int ks = 0; ks < 16; ++ks) {
            const u32x4 a1 = sb[ks * 64 + lane];          // gate
            const u32x4 a2 = sb[1024 + ks * 64 + lane];   // up
            zg = __builtin_amdgcn_mfma_f32_32x32x16_bf16(
                     __builtin_bit_cast(bf16x8, a1),
                     __builtin_bit_cast(bf16x8, xf[ks]), zg, 0, 0, 0);
            zu = __builtin_amdgcn_mfma_f32_32x32x16_bf16(
                     __builtin_bit_cast(bf16x8, a2),
                     __builtin_bit_cast(bf16x8, xf[ks]), zu, 0, 0, 0);
        }
        __builtin_amdgcn_s_setprio(0);

        // ---- act: h = silu(zg)*zu, packed in-register (A-frag == natural reg order)
        float hv[16];
        #pragma unroll
        for (int i = 0; i < 16; ++i) {
            const float gv = zg[i];
            const float s  = __builtin_amdgcn_rcpf(1.0f + __expf(-gv));
            hv[i] = gv * s * zu[i];
        }
        const u32x4 ha0 = u32x4{ cvtpk(hv[0], hv[1]),   cvtpk(hv[2], hv[3]),
                                 cvtpk(hv[4], hv[5]),   cvtpk(hv[6], hv[7]) };
        const u32x4 ha1 = u32x4{ cvtpk(hv[8], hv[9]),   cvtpk(hv[10], hv[11]),
                                 cvtpk(hv[12], hv[13]), cvtpk(hv[14], hv[15]) };
        const bf16x8 A0 = __builtin_bit_cast(bf16x8, ha0);
        const bf16x8 A1 = __builtin_bit_cast(bf16x8, ha1);

        // ---- GEMM2: acc += h(32tok x 32f) * Wd(32f x 256), Wd DIRECT from L2.
        // <=8 loads (32 VGPRs, reusing dead zg/zu) in flight; counted vmcnt.
        {
            const u32x4* wdc = wcg + (size_t)c * 3072 + 2048 + lane;
            u32x4 wa0 = gld16(wdc + 0 * 64), wa1 = gld16(wdc + 1 * 64),
                  wa2 = gld16(wdc + 2 * 64), wa3 = gld16(wdc + 3 * 64);
            u32x4 wb0 = gld16(wdc + 4 * 64), wb1 = gld16(wdc + 5 * 64),
                  wb2 = gld16(wdc + 6 * 64), wb3 = gld16(wdc + 7 * 64);

            asm volatile("s_waitcnt vmcnt(4)" ::: "memory");   // wa0..3 (+staging) done
            __builtin_amdgcn_sched_barrier(0);
            __builtin_amdgcn_s_setprio(1);
            acc[0] = __builtin_amdgcn_mfma_f32_32x32x16_bf16(A0, __builtin_bit_cast(bf16x8, wa0), acc[0], 0, 0, 0);
            acc[1] = __builtin_amdgcn_mfma_f32_32x32x16_bf16(A0, __builtin_bit_cast(bf16x8, wa1), acc[1], 0, 0, 0);
            acc[2] = __builtin_amdgcn_mfma_f32_32x32x16_bf16(A0, __builtin_bit_cast(bf16x8, wa2), acc[2], 0, 0, 0);
            acc[3] = __builtin_amdgcn_mfma_f32_32x32x16_bf16(A0, __builtin_bit_cast(bf16x8, wa3), acc[3], 0, 0, 0);
            __builtin_amdgcn_s_setprio(0);

            wa0 = gld16(wdc + 8 * 64);  wa1 = gld16(wdc + 9 * 64);
            wa2 = gld16(wdc + 10 * 64); wa3 = gld16(wdc + 11 * 64);
            asm volatile("s_waitcnt vmcnt(4)" ::: "memory");   // wb0..3 done
            __builtin_amdgcn_sched_barrier(0);
            __builtin_amdgcn_s_setprio(1);
            acc[4] = __builtin_amdgcn_mfma_f32_32x32x16_bf16(A0, __builtin_bit_cast(bf16x8, wb0), acc[4], 0, 0, 0);
            acc[5] = __builtin_amdgcn_mfma_f32_32x32x16_bf16(A0, __builtin_bit_cast(bf16x8, wb1), acc[5], 0, 0, 0);
            acc[6] = __builtin_amdgcn_mfma_f32_32x32x16_bf16(A0, __builtin_bit_cast(bf16x8, wb2), acc[6], 0, 0, 0);
            acc[7] = __builtin_amdgcn_mfma_f32_32x32x16_bf16(A0, __builtin_bit_cast(bf16x8, wb3), acc[7], 0, 0, 0);
            __builtin_amdgcn_s_setprio(0);

            wb0 = gld16(wdc + 12 * 64); wb1 = gld16(wdc + 13 * 64);
            wb2 = gld16(wdc + 14 * 64); wb3 = gld16(wdc + 15 * 64);
            asm volatile("s_waitcnt vmcnt(4)" ::: "memory");   // wa (frags 8..11) done
            __builtin_amdgcn_sched_barrier(0);
            __builtin_amdgcn_s_setprio(1);
            acc[0] = __builtin_amdgcn_mfma_f32_32x32x16_bf16(A1, __builtin_bit_cast(bf16x8, wa0), acc[0], 0, 0, 0);
            acc[1] = __builtin_amdgcn_mfma_f32_32x32x16_bf16(A1, __builtin_bit_cast(bf16x8, wa1), acc[1], 0, 0, 0);
            acc[2] = __builtin_amdgcn_mfma_f32_32x32x16_bf16(A1, __builtin_bit_cast(bf16x8, wa2), acc[2], 0, 0, 0);
            acc[3] = __builtin_amdgcn_mfma_f32_32x32x16_bf16(A1, __builtin_bit_cast(bf16x8, wa3), acc[3], 0, 0, 0);
            __builtin_amdgcn_s_setprio(0);

            asm volatile("s_waitcnt vmcnt(0)" ::: "memory");   // all (incl. staging c+2)
            __builtin_amdgcn_sched_barrier(0);
            __builtin_amdgcn_s_setprio(1);
            acc[4] = __builtin_amdgcn_mfma_f32_32x32x16_bf16(A1, __builtin_bit_cast(bf16x8, wb0), acc[4], 0, 0, 0);
            acc[5] = __builtin_amdgcn_mfma_f32_32x32x16_bf16(A1, __builtin_bit_cast(bf16x8, wb1), acc[5], 0, 0, 0);
            acc[6] = __builtin_amdgcn_mfma_f32_32x32x16_bf16(A1, __builtin_bit_cast(bf16x8, wb2), acc[6], 0, 0, 0);
            acc[7] = __builtin_amdgcn_mfma_f32_32x32x16_bf16(A1, __builtin_bit_cast(bf16x8, wb3), acc[7], 0, 0, 0);
            __builtin_amdgcn_s_setprio(0);
        }

        bcur = (bcur == 2) ? 0 : bcur + 1;
    }

    // epilogue: C layout -> y fp32
    float* yp = y + (size_t)(m0 + w * 32) * DMODEL;
    #pragma unroll
    for (int nb = 0; nb < 8; ++nb) {
        const int col = nb * 32 + l31;
        #pragma unroll
        for (int r = 0; r < 16; ++r) {
            const int row = (r & 3) + (r >> 2) * 8 + q * 4;
            yp[(size_t)row * DMODEL + col] = acc[nb][r];
        }
    }
}

extern "C" void kernel_launch(void* const* d_in, const int* in_sizes, int n_in,
                              void* d_out, int out_size, void* d_ws, size_t ws_size,
                              hipStream_t stream) {
    const float* x  = (const float*)d_in[0];
    const float* wg = (const float*)d_in[1];
    const float* wu = (const float*)d_in[2];
    const float* wd = (const float*)d_in[3];
    float* y = (float*)d_out;

    // ws: wcomb only (12.6 MB); x is consumed fp32 directly by k_glu
    u32x4* wcomb = (u32x4*)d_ws;   // 8*32*48*64 = 786432 u32x4

    k_prep_w<<<dim3(3072), dim3(256), 0, stream>>>(wg, wu, wd, wcomb);
    k_glu<<<dim3(512), dim3(512), 0, stream>>>(x, wcomb, y);
}

// Round 4
// 428.010 us; speedup vs baseline: 1.0042x; 1.0042x over previous
//
#include <hip/hip_runtime.h>

typedef __bf16 bf16x8 __attribute__((ext_vector_type(8)));
typedef float f32x16 __attribute__((ext_vector_type(16)));
typedef unsigned int u32x4 __attribute__((ext_vector_type(4)));

#define NGROUP 8
#define DMODEL 256
#define DFF    1024
#define TTOT   131072
#define TGRP   (TTOT / NGROUP)   // 16384
#define MTILE  128               // tokens per block (4 waves x 32)
#define NCHUNK 32                // f-chunks of 32 (DFF/32)
// Block = 4 waves (256 thr), LDS = 64 KB (two 32KB gate+up buffers) so TWO
// blocks co-reside per CU (2 waves/SIMD from DIFFERENT blocks -> latency
// stalls of one block are covered by the other; no shared barriers).
//   buf b at u32x4 offset b*2048:
//     [   0, 16K)  gate A-frags [ks(16)][lane(64)] x 16B
//     [ 16K, 32K)  up   A-frags
// Wd: loaded per-wave straight from L2 into VGPRs (vmem pipe, 8-deep window).
// h never touches LDS (k-permuted Wd makes packed GEMM1 acc == GEMM2 A-frag).
// ONE s_barrier per chunk. Staging for c+1 is issued at the TOP of iter c
// (buffer freed by the barrier; a whole GEMM1 elapses before anything waits
// on vmem, so the staging is retired by then -- no coupling stall).

__device__ __forceinline__ unsigned int f2bf(float f) {
    unsigned int x = __builtin_bit_cast(unsigned int, f);
    return (x + 0x7fffu + ((x >> 16) & 1u)) >> 16;   // RNE
}
__device__ __forceinline__ unsigned int pack2(float lo, float hi) {
    return f2bf(lo) | (f2bf(hi) << 16);
}
__device__ __forceinline__ unsigned int cvtpk(float lo, float hi) {
    unsigned int r;
    asm("v_cvt_pk_bf16_f32 %0, %1, %2" : "=v"(r) : "v"(lo), "v"(hi));  // RNE
    return r;
}

__device__ __forceinline__ void g2l(const void* g, void* l) {
    __builtin_amdgcn_global_load_lds(
        (const __attribute__((address_space(1))) unsigned int*)g,
        (__attribute__((address_space(3))) unsigned int*)l, 16, 0, 0);
}

__device__ __forceinline__ u32x4 gld16(const u32x4* p) {
    u32x4 d;
    asm volatile("global_load_dwordx4 %0, %1, off" : "=v"(d) : "v"(p) : "memory");
    return d;
}

// ---------------- prep: all weights -> per-(group,chunk) 48KB frag blocks ----------------
//   fid 0..15  : gate A-frag, ks=fid      W[d=ks*16+q*8+j][f=c*32+l31]
//   fid 16..31 : up   A-frag, ks=fid-16
//   fid 32..47 : down B-frag, ks2=(fid-32)>>3, nb=(fid-32)&7
//     k-axis PERMUTED to match packed-accumulator A-frags:
//     B[k=q*8+j] = Wd[F = c*32 + ks2*16 + q*4 + (j&3) + 8*(j>>2)][col=nb*32+l31]
__global__ void k_prep_w(const float* __restrict__ wg, const float* __restrict__ wu,
                         const float* __restrict__ wd, u32x4* __restrict__ out) {
    int t = blockIdx.x * 256 + threadIdx.x;   // 786432 total
    int lane = t & 63;
    int q = lane >> 5, l31 = lane & 31;
    int fg = t >> 6;
    int fid = fg % 48;
    int gc  = fg / 48;
    int c = gc & 31, g = gc >> 5;
    u32x4 v;
    if (fid < 32) {
        const float* w = (fid < 16) ? wg : wu;
        int ks = fid & 15;
        const float* src = w + (size_t)(g * 256 + ks * 16 + q * 8) * 1024 + c * 32 + l31;
        v = u32x4{ pack2(src[0],        src[1024]),
                   pack2(src[2 * 1024], src[3 * 1024]),
                   pack2(src[4 * 1024], src[5 * 1024]),
                   pack2(src[6 * 1024], src[7 * 1024]) };
    } else {
        int idx = fid - 32;
        int ks2 = idx >> 3, nb = idx & 7;
        // rows f = base + {0,1,2,3, 8,9,10,11}  (permuted k-axis)
        const float* src = wd + (size_t)(g * 1024 + c * 32 + ks2 * 16 + q * 4) * 256 + nb * 32 + l31;
        v = u32x4{ pack2(src[0 * 256],  src[1 * 256]),
                   pack2(src[2 * 256],  src[3 * 256]),
                   pack2(src[8 * 256],  src[9 * 256]),
                   pack2(src[10 * 256], src[11 * 256]) };
    }
    out[t] = v;
}

// ---------------- main fused grouped-GLU ----------------
__global__ __launch_bounds__(256, 2)
void k_glu(const float* __restrict__ x,      // fp32 x row-major [T][256]
           const u32x4* __restrict__ wcomb,  // [g][c][48 frag-groups][64 lanes]
           float* __restrict__ y) {
    __shared__ u32x4 smem[4096];   // 64 KB: two 32KB buffers

    const int tid  = threadIdx.x;
    const int lane = tid & 63;
    const int w    = tid >> 6;      // wave 0..3 = token-32 block
    const int q    = lane >> 5;
    const int l31  = lane & 31;

    // XCD swizzle: group = blockIdx & 7 so each XCD's L2 holds one group's weights
    const int g    = blockIdx.x & 7;
    const int m0   = g * TGRP + (blockIdx.x >> 3) * MTILE;
    const int tok  = m0 + w * 32 + l31;

    const u32x4* wcg = wcomb + (size_t)(g * 32) * 3072;

    // ---- prologue: stage chunk 0 -> buf0 (8 g2l per wave), x -> bf16 B-frags
    #pragma unroll
    for (int i = 0; i < 8; ++i) {
        int off = i * 256 + w * 64;   // u32x4 index, wave-uniform LDS dest
        g2l(wcg + off + lane, smem + off);
    }
    u32x4 xf[16];
    {
        const float* xrow = x + (size_t)tok * DMODEL + q * 8;
        #pragma unroll
        for (int ks = 0; ks < 16; ++ks) {
            float4 a = *(const float4*)(xrow + ks * 16);
            float4 b = *(const float4*)(xrow + ks * 16 + 4);
            xf[ks] = u32x4{ cvtpk(a.x, a.y), cvtpk(a.z, a.w),
                            cvtpk(b.x, b.y), cvtpk(b.z, b.w) };
        }
    }

    f32x16 acc[8];
    #pragma unroll
    for (int nb = 0; nb < 8; ++nb)
        #pragma unroll
        for (int i = 0; i < 16; ++i) acc[nb][i] = 0.0f;

    for (int c = 0; c < NCHUNK; ++c) {
        const u32x4* sb = smem + (c & 1) * 2048;

        // top sync: own vmem drained (staging c is old by now), publish cross-wave
        asm volatile("s_waitcnt vmcnt(0)" ::: "memory");
        __builtin_amdgcn_s_barrier();
        asm volatile("" ::: "memory");

        // ---- stage chunk c+1 into buf[(c+1)&1] (freed by the barrier above);
        //      a full GEMM1 elapses before the ladder's first wait -> retired by then
        if (c + 1 < NCHUNK) {
            u32x4* db = smem + ((c + 1) & 1) * 2048;
            const u32x4* gsrc = wcg + (size_t)(c + 1) * 3072;
            #pragma unroll
            for (int i = 0; i < 8; ++i) {
                int off = i * 256 + w * 64;
                g2l(gsrc + off + lane, db + off);
            }
        }

        // ---- GEMM1: z^T (32f x 32tok) over K=256, gate/up from LDS, x from regs
        f32x16 zg, zu;
        #pragma unroll
        for (int i = 0; i < 16; ++i) { zg[i] = 0.0f; zu[i] = 0.0f; }
        __builtin_amdgcn_s_setprio(1);
        #pragma unroll
        for (int ks = 0; ks < 16; ++ks) {
            const u32x4 a1 = sb[ks * 64 + lane];          // gate
            const u32x4 a2 = sb[1024 + ks * 64 + lane];   // up
            zg = __builtin_amdgcn_mfma_f32_32x32x16_bf16(
                     __builtin_bit_cast(bf16x8, a1),
                     __builtin_bit_cast(bf16x8, xf[ks]), zg, 0, 0, 0);
            zu = __builtin_amdgcn_mfma_f32_32x32x16_bf16(
                     __builtin_bit_cast(bf16x8, a2),
                     __builtin_bit_cast(bf16x8, xf[ks]), zu, 0, 0, 0);
        }
        __builtin_amdgcn_s_setprio(0);

        // ---- first Wd batch issued BEFORE act: ~150 cyc extra latency cover
        const u32x4* wdc = wcg + (size_t)c * 3072 + 2048 + lane;
        u32x4 wa0 = gld16(wdc + 0 * 64), wa1 = gld16(wdc + 1 * 64),
              wa2 = gld16(wdc + 2 * 64), wa3 = gld16(wdc + 3 * 64);

        // ---- act: h = silu(zg)*zu, packed in-register (A-frag == natural reg order)
        float hv[16];
        #pragma unroll
        for (int i = 0; i < 16; ++i) {
            const float gv = zg[i];
            const float s  = __builtin_amdgcn_rcpf(1.0f + __expf(-gv));
            hv[i] = gv * s * zu[i];
        }
        const u32x4 ha0 = u32x4{ cvtpk(hv[0], hv[1]),   cvtpk(hv[2], hv[3]),
                                 cvtpk(hv[4], hv[5]),   cvtpk(hv[6], hv[7]) };
        const u32x4 ha1 = u32x4{ cvtpk(hv[8], hv[9]),   cvtpk(hv[10], hv[11]),
                                 cvtpk(hv[12], hv[13]), cvtpk(hv[14], hv[15]) };
        const bf16x8 A0 = __builtin_bit_cast(bf16x8, ha0);
        const bf16x8 A1 = __builtin_bit_cast(bf16x8, ha1);

        // ---- GEMM2: acc += h(32tok x 32f) * Wd(32f x 256), Wd direct from L2.
        // 8-deep window; counted vmcnt; staging (oldest in FIFO) is long retired.
        u32x4 wb0 = gld16(wdc + 4 * 64), wb1 = gld16(wdc + 5 * 64),
              wb2 = gld16(wdc + 6 * 64), wb3 = gld16(wdc + 7 * 64);

        asm volatile("s_waitcnt vmcnt(4)" ::: "memory");   // wa0..3 ready
        __builtin_amdgcn_sched_barrier(0);
        __builtin_amdgcn_s_setprio(1);
        acc[0] = __builtin_amdgcn_mfma_f32_32x32x16_bf16(A0, __builtin_bit_cast(bf16x8, wa0), acc[0], 0, 0, 0);
        acc[1] = __builtin_amdgcn_mfma_f32_32x32x16_bf16(A0, __builtin_bit_cast(bf16x8, wa1), acc[1], 0, 0, 0);
        acc[2] = __builtin_amdgcn_mfma_f32_32x32x16_bf16(A0, __builtin_bit_cast(bf16x8, wa2), acc[2], 0, 0, 0);
        acc[3] = __builtin_amdgcn_mfma_f32_32x32x16_bf16(A0, __builtin_bit_cast(bf16x8, wa3), acc[3], 0, 0, 0);
        __builtin_amdgcn_s_setprio(0);

        wa0 = gld16(wdc + 8 * 64);  wa1 = gld16(wdc + 9 * 64);
        wa2 = gld16(wdc + 10 * 64); wa3 = gld16(wdc + 11 * 64);
        asm volatile("s_waitcnt vmcnt(4)" ::: "memory");   // wb0..3 ready
        __builtin_amdgcn_sched_barrier(0);
        __builtin_amdgcn_s_setprio(1);
        acc[4] = __builtin_amdgcn_mfma_f32_32x32x16_bf16(A0, __builtin_bit_cast(bf16x8, wb0), acc[4], 0, 0, 0);
        acc[5] = __builtin_amdgcn_mfma_f32_32x32x16_bf16(A0, __builtin_bit_cast(bf16x8, wb1), acc[5], 0, 0, 0);
        acc[6] = __builtin_amdgcn_mfma_f32_32x32x16_bf16(A0, __builtin_bit_cast(bf16x8, wb2), acc[6], 0, 0, 0);
        acc[7] = __builtin_amdgcn_mfma_f32_32x32x16_bf16(A0, __builtin_bit_cast(bf16x8, wb3), acc[7], 0, 0, 0);
        __builtin_amdgcn_s_setprio(0);

        wb0 = gld16(wdc + 12 * 64); wb1 = gld16(wdc + 13 * 64);
        wb2 = gld16(wdc + 14 * 64); wb3 = gld16(wdc + 15 * 64);
        asm volatile("s_waitcnt vmcnt(4)" ::: "memory");   // wa (frags 8..11) ready
        __builtin_amdgcn_sched_barrier(0);
        __builtin_amdgcn_s_setprio(1);
        acc[0] = __builtin_amdgcn_mfma_f32_32x32x16_bf16(A1, __builtin_bit_cast(bf16x8, wa0), acc[0], 0, 0, 0);
        acc[1] = __builtin_amdgcn_mfma_f32_32x32x16_bf16(A1, __builtin_bit_cast(bf16x8, wa1), acc[1], 0, 0, 0);
        acc[2] = __builtin_amdgcn_mfma_f32_32x32x16_bf16(A1, __builtin_bit_cast(bf16x8, wa2), acc[2], 0, 0, 0);
        acc[3] = __builtin_amdgcn_mfma_f32_32x32x16_bf16(A1, __builtin_bit_cast(bf16x8, wa3), acc[3], 0, 0, 0);
        __builtin_amdgcn_s_setprio(0);

        asm volatile("s_waitcnt vmcnt(0)" ::: "memory");   // wb (frags 12..15) ready
        __builtin_amdgcn_sched_barrier(0);
        __builtin_amdgcn_s_setprio(1);
        acc[4] = __builtin_amdgcn_mfma_f32_32x32x16_bf16(A1, __builtin_bit_cast(bf16x8, wb0), acc[4], 0, 0, 0);
        acc[5] = __builtin_amdgcn_mfma_f32_32x32x16_bf16(A1, __builtin_bit_cast(bf16x8, wb1), acc[5], 0, 0, 0);
        acc[6] = __builtin_amdgcn_mfma_f32_32x32x16_bf16(A1, __builtin_bit_cast(bf16x8, wb2), acc[6], 0, 0, 0);
        acc[7] = __builtin_amdgcn_mfma_f32_32x32x16_bf16(A1, __builtin_bit_cast(bf16x8, wb3), acc[7], 0, 0, 0);
        __builtin_amdgcn_s_setprio(0);
    }

    // epilogue: C layout -> y fp32
    float* yp = y + (size_t)(m0 + w * 32) * DMODEL;
    #pragma unroll
    for (int nb = 0; nb < 8; ++nb) {
        const int col = nb * 32 + l31;
        #pragma unroll
        for (int r = 0; r < 16; ++r) {
            const int row = (r & 3) + (r >> 2) * 8 + q * 4;
            yp[(size_t)row * DMODEL + col] = acc[nb][r];
        }
    }
}

extern "C" void kernel_launch(void* const* d_in, const int* in_sizes, int n_in,
                              void* d_out, int out_size, void* d_ws, size_t ws_size,
                              hipStream_t stream) {
    const float* x  = (const float*)d_in[0];
    const float* wg = (const float*)d_in[1];
    const float* wu = (const float*)d_in[2];
    const float* wd = (const float*)d_in[3];
    float* y = (float*)d_out;

    // ws: wcomb only (12.6 MB); x is consumed fp32 directly by k_glu
    u32x4* wcomb = (u32x4*)d_ws;   // 8*32*48*64 = 786432 u32x4

    k_prep_w<<<dim3(3072), dim3(256), 0, stream>>>(wg, wu, wd, wcomb);
    k_glu<<<dim3(1024), dim3(256), 0, stream>>>(x, wcomb, y);
}

// Round 5
// 414.900 us; speedup vs baseline: 1.0360x; 1.0316x over previous
//
#include <hip/hip_runtime.h>

typedef __bf16 bf16x8 __attribute__((ext_vector_type(8)));
typedef float f32x16 __attribute__((ext_vector_type(16)));
typedef unsigned int u32x4 __attribute__((ext_vector_type(4)));

#define NGROUP 8
#define DMODEL 256
#define DFF    1024
#define TTOT   131072
#define TGRP   (TTOT / NGROUP)   // 16384
#define MTILE  256               // tokens per block (8 waves x 32)
#define NCHUNK 32                // f-chunks of 32 (DFF/32)
// LDS map (144 KB static): THREE 48KB chunk buffers (gate+up+down, triple-buffered).
//   buf s at u32x4 offset s*3072:
//     [   0, 16K)  gate A-frags [ks(16)][lane(64)] x 16B
//     [ 16K, 32K)  up   A-frags
//     [ 32K, 48K)  down B-frags [frag(16)][lane(64)] x 16B (k-permuted at prep)
// h pipelined ACROSS the chunk boundary: iteration c interleaves GEMM1(c)
// (reads buf c%3) with GEMM2(c-1) (reads buf (c-1)%3, h(c-1) in 8 regs) --
// every unrolled step is {3 ds_read + 3 MFMA}, so the LDS pipe never idles
// behind a phase boundary. Staging (c+1 -> buf (c+1)%3) is issued right after
// the single per-chunk barrier and waited one full interleaved phase later.
// Triple buffer makes {read c, read c-1, write c+1} slots all distinct.

__device__ __forceinline__ unsigned int f2bf(float f) {
    unsigned int x = __builtin_bit_cast(unsigned int, f);
    return (x + 0x7fffu + ((x >> 16) & 1u)) >> 16;   // RNE
}
__device__ __forceinline__ unsigned int pack2(float lo, float hi) {
    return f2bf(lo) | (f2bf(hi) << 16);
}
__device__ __forceinline__ unsigned int cvtpk(float lo, float hi) {
    unsigned int r;
    asm("v_cvt_pk_bf16_f32 %0, %1, %2" : "=v"(r) : "v"(lo), "v"(hi));  // RNE
    return r;
}

__device__ __forceinline__ void g2l(const void* g, void* l) {
    __builtin_amdgcn_global_load_lds(
        (const __attribute__((address_space(1))) unsigned int*)g,
        (__attribute__((address_space(3))) unsigned int*)l, 16, 0, 0);
}

// ---------------- prep: all weights -> per-(group,chunk) 48KB frag blocks ----------------
//   fid 0..15  : gate A-frag, ks=fid      W[d=ks*16+q*8+j][f=c*32+l31]
//   fid 16..31 : up   A-frag, ks=fid-16
//   fid 32..47 : down B-frag, ks2=(fid-32)>>3, nb=(fid-32)&7
//     k-axis PERMUTED to match packed-accumulator A-frags:
//     B[k=q*8+j] = Wd[F = c*32 + ks2*16 + q*4 + (j&3) + 8*(j>>2)][col=nb*32+l31]
__global__ void k_prep_w(const float* __restrict__ wg, const float* __restrict__ wu,
                         const float* __restrict__ wd, u32x4* __restrict__ out) {
    int t = blockIdx.x * 256 + threadIdx.x;   // 786432 total
    int lane = t & 63;
    int q = lane >> 5, l31 = lane & 31;
    int fg = t >> 6;
    int fid = fg % 48;
    int gc  = fg / 48;
    int c = gc & 31, g = gc >> 5;
    u32x4 v;
    if (fid < 32) {
        const float* w = (fid < 16) ? wg : wu;
        int ks = fid & 15;
        const float* src = w + (size_t)(g * 256 + ks * 16 + q * 8) * 1024 + c * 32 + l31;
        v = u32x4{ pack2(src[0],        src[1024]),
                   pack2(src[2 * 1024], src[3 * 1024]),
                   pack2(src[4 * 1024], src[5 * 1024]),
                   pack2(src[6 * 1024], src[7 * 1024]) };
    } else {
        int idx = fid - 32;
        int ks2 = idx >> 3, nb = idx & 7;
        // rows f = base + {0,1,2,3, 8,9,10,11}  (permuted k-axis)
        const float* src = wd + (size_t)(g * 1024 + c * 32 + ks2 * 16 + q * 4) * 256 + nb * 32 + l31;
        v = u32x4{ pack2(src[0 * 256],  src[1 * 256]),
                   pack2(src[2 * 256],  src[3 * 256]),
                   pack2(src[8 * 256],  src[9 * 256]),
                   pack2(src[10 * 256], src[11 * 256]) };
    }
    out[t] = v;
}

#define MFMA(A, B, C) __builtin_amdgcn_mfma_f32_32x32x16_bf16( \
        __builtin_bit_cast(bf16x8, A), __builtin_bit_cast(bf16x8, B), C, 0, 0, 0)

// ---------------- main fused grouped-GLU ----------------
__global__ __launch_bounds__(512, 2)
void k_glu(const float* __restrict__ x,      // fp32 x row-major [T][256]
           const u32x4* __restrict__ wcomb,  // [g][c][48 frag-groups][64 lanes]
           float* __restrict__ y) {
    __shared__ u32x4 smem[9216];   // 144 KB: three 48KB buffers

    const int tid  = threadIdx.x;
    const int lane = tid & 63;
    const int w    = tid >> 6;      // wave 0..7 = token-32 block
    const int q    = lane >> 5;
    const int l31  = lane & 31;

    // XCD swizzle: group = blockIdx & 7 so each XCD's L2 holds one group's weights
    const int g    = blockIdx.x & 7;
    const int m0   = g * TGRP + (blockIdx.x >> 3) * MTILE;
    const int tok  = m0 + w * 32 + l31;

    const u32x4* wcg = wcomb + (size_t)(g * 32) * 3072;

    // ---- prologue: stage chunk0 -> buf0, chunk1 -> buf1 (6 g2l each per wave)
    #pragma unroll
    for (int i = 0; i < 6; ++i) {
        int off = i * 512 + w * 64;   // u32x4 index, wave-uniform LDS dest
        g2l(wcg + off + lane, smem + off);
    }
    #pragma unroll
    for (int i = 0; i < 6; ++i) {
        int off = i * 512 + w * 64;
        g2l(wcg + 3072 + off + lane, smem + 3072 + off);
    }
    // x -> bf16 B-frags, register-resident for the whole block
    u32x4 xf[16];
    {
        const float* xrow = x + (size_t)tok * DMODEL + q * 8;
        #pragma unroll
        for (int ks = 0; ks < 16; ++ks) {
            float4 a = *(const float4*)(xrow + ks * 16);
            float4 b = *(const float4*)(xrow + ks * 16 + 4);
            xf[ks] = u32x4{ cvtpk(a.x, a.y), cvtpk(a.z, a.w),
                            cvtpk(b.x, b.y), cvtpk(b.z, b.w) };
        }
    }

    f32x16 acc[8];
    #pragma unroll
    for (int nb = 0; nb < 8; ++nb)
        #pragma unroll
        for (int i = 0; i < 16; ++i) acc[nb][i] = 0.0f;

    asm volatile("s_waitcnt vmcnt(0)" ::: "memory");   // chunks 0/1 staged
    __builtin_amdgcn_s_barrier();
    asm volatile("" ::: "memory");

    u32x4 A0, A1;   // h fragments of the previous chunk (pipelined)

    // ---- peel c = 0: GEMM1(0) + act(0), no GEMM2 yet
    {
        const u32x4* sb = smem;
        f32x16 zg, zu;
        #pragma unroll
        for (int i = 0; i < 16; ++i) { zg[i] = 0.0f; zu[i] = 0.0f; }
        #pragma unroll
        for (int ks = 0; ks < 16; ++ks) {
            const u32x4 a1 = sb[ks * 64 + lane];
            const u32x4 a2 = sb[1024 + ks * 64 + lane];
            zg = MFMA(a1, xf[ks], zg);
            zu = MFMA(a2, xf[ks], zu);
        }
        float hv[16];
        #pragma unroll
        for (int i = 0; i < 16; ++i) {
            const float gv = zg[i];
            const float s  = __builtin_amdgcn_rcpf(1.0f + __expf(-gv));
            hv[i] = gv * s * zu[i];
        }
        A0 = u32x4{ cvtpk(hv[0], hv[1]),   cvtpk(hv[2], hv[3]),
                    cvtpk(hv[4], hv[5]),   cvtpk(hv[6], hv[7]) };
        A1 = u32x4{ cvtpk(hv[8], hv[9]),   cvtpk(hv[10], hv[11]),
                    cvtpk(hv[12], hv[13]), cvtpk(hv[14], hv[15]) };
    }

    // ---- steady state: iteration c does GEMM1(c) || GEMM2(c-1), then act(c)
    int bc = 1, bp = 0, bn = 2;   // buf slots: current, previous, next (c%3 etc.)
    for (int c = 1; c < NCHUNK; ++c) {
        const u32x4* sbc = smem + bc * 3072;
        const u32x4* sbp = smem + bp * 3072;

        asm volatile("s_waitcnt vmcnt(0)" ::: "memory");   // staging c (issued iter c-1) done
        __builtin_amdgcn_s_barrier();                      // buf (c+1)%3's readers finished
        asm volatile("" ::: "memory");

        if (c + 1 < NCHUNK) {
            u32x4* db = smem + bn * 3072;
            const u32x4* gsrc = wcg + (size_t)(c + 1) * 3072;
            #pragma unroll
            for (int i = 0; i < 6; ++i) {
                int off = i * 512 + w * 64;
                g2l(gsrc + off + lane, db + off);
            }
        }

        // interleaved: per ks = {3 ds_read + 3 MFMA}; uniform pipe mix
        f32x16 zg, zu;
        #pragma unroll
        for (int i = 0; i < 16; ++i) { zg[i] = 0.0f; zu[i] = 0.0f; }
        #pragma unroll
        for (int ks = 0; ks < 16; ++ks) {
            const u32x4 a1 = sbc[ks * 64 + lane];          // gate(c)
            const u32x4 a2 = sbc[1024 + ks * 64 + lane];   // up(c)
            const u32x4 bd = sbp[2048 + ks * 64 + lane];   // Wd(c-1) frag ks
            zg = MFMA(a1, xf[ks], zg);
            zu = MFMA(a2, xf[ks], zu);
            if (ks < 8) acc[ks]     = MFMA(A0, bd, acc[ks]);
            else        acc[ks - 8] = MFMA(A1, bd, acc[ks - 8]);
        }

        // act(c): h -> A0/A1 for the next iteration's GEMM2
        float hv[16];
        #pragma unroll
        for (int i = 0; i < 16; ++i) {
            const float gv = zg[i];
            const float s  = __builtin_amdgcn_rcpf(1.0f + __expf(-gv));
            hv[i] = gv * s * zu[i];
        }
        A0 = u32x4{ cvtpk(hv[0], hv[1]),   cvtpk(hv[2], hv[3]),
                    cvtpk(hv[4], hv[5]),   cvtpk(hv[6], hv[7]) };
        A1 = u32x4{ cvtpk(hv[8], hv[9]),   cvtpk(hv[10], hv[11]),
                    cvtpk(hv[12], hv[13]), cvtpk(hv[14], hv[15]) };

        const int t = bp; bp = bc; bc = bn; bn = t;   // rotate buffers
    }

    // ---- drain: GEMM2(31) from buf (31 % 3) == bp after final rotate
    {
        const u32x4* sbp = smem + bp * 3072;
        #pragma unroll
        for (int ks = 0; ks < 16; ++ks) {
            const u32x4 bd = sbp[2048 + ks * 64 + lane];
            if (ks < 8) acc[ks]     = MFMA(A0, bd, acc[ks]);
            else        acc[ks - 8] = MFMA(A1, bd, acc[ks - 8]);
        }
    }

    // epilogue: C layout -> y fp32
    float* yp = y + (size_t)(m0 + w * 32) * DMODEL;
    #pragma unroll
    for (int nb = 0; nb < 8; ++nb) {
        const int col = nb * 32 + l31;
        #pragma unroll
        for (int r = 0; r < 16; ++r) {
            const int row = (r & 3) + (r >> 2) * 8 + q * 4;
            yp[(size_t)row * DMODEL + col] = acc[nb][r];
        }
    }
}

extern "C" void kernel_launch(void* const* d_in, const int* in_sizes, int n_in,
                              void* d_out, int out_size, void* d_ws, size_t ws_size,
                              hipStream_t stream) {
    const float* x  = (const float*)d_in[0];
    const float* wg = (const float*)d_in[1];
    const float* wu = (const float*)d_in[2];
    const float* wd = (const float*)d_in[3];
    float* y = (float*)d_out;

    // ws: wcomb only (12.6 MB); x is consumed fp32 directly by k_glu
    u32x4* wcomb = (u32x4*)d_ws;   // 8*32*48*64 = 786432 u32x4

    k_prep_w<<<dim3(3072), dim3(256), 0, stream>>>(wg, wu, wd, wcomb);
    k_glu<<<dim3(512), dim3(512), 0, stream>>>(x, wcomb, y);
}